// Round 4
// baseline (542.762 us; speedup 1.0000x reference)
//
#include <hip/hip_runtime.h>
#include <cstdint>
#include <cstddef>

#define BATCH 2048
#define VOCAB 50257
#define TOPK  512
#define BLOCK 256
#define SLOTS 16            // per-thread candidate capacity
#define STRIDE 17           // LDS words per thread bucket (odd -> conflict-free)
#define CAND_MAX (BLOCK * SLOTS)   // 4096

// Native clang vector type — __builtin_nontemporal_load requires this.
typedef float vfloat4 __attribute__((ext_vector_type(4)));

// Monotone mapping: float -> unsigned such that key order == value order.
__device__ __forceinline__ unsigned fkey(float f) {
    unsigned u = __float_as_uint(f);
    return (u & 0x80000000u) ? ~u : (u | 0x80000000u);
}
__device__ __forceinline__ float unfkey(unsigned k) {
    unsigned u = (k & 0x80000000u) ? (k & 0x7FFFFFFFu) : ~k;
    return __uint_as_float(u);
}

__global__ __launch_bounds__(BLOCK) void topk_ce_kernel(
    const float* __restrict__ feats,
    const int*   __restrict__ labels,
    float*       __restrict__ out)
{
    __shared__ float    buck[BLOCK * STRIDE];   // 17408 B: per-thread buckets, then compacted candidates
    __shared__ unsigned s_pfx[BLOCK];           // count prefix-scan / radix suffix-scan scratch
    __shared__ unsigned s_hist[256];
    __shared__ int      s_dig, s_above, s_ovf;
    __shared__ float    s_red0[BLOCK / 64];
    __shared__ float    s_red1[BLOCK / 64];

    const int row = blockIdx.x;
    const int tid = threadIdx.x;
    const float* rp = feats + (size_t)row * VOCAB;
    const int bbase = tid * STRIDE;

    // Row base is only 4B-aligned (VOCAB*4 % 16 == 4). Peel to 16B alignment.
    uintptr_t a = (uintptr_t)rp;
    int head = ((int)((16u - (a & 15u)) & 15u)) >> 2;
    if (head > VOCAB) head = VOCAB;
    const int nvec = (VOCAB - head) >> 2;
    const int tailstart = head + nvec * 4;
    const vfloat4* vp = (const vfloat4*)(rp + head);
    const int nfull = nvec / (BLOCK * 4);
    const int restart = nfull * BLOCK * 4;

    // --- Scan: branchless, atomic-free append into per-thread LDS buckets.
    // "Store at slot cnt unconditionally, advance cnt on accept": slot cnt is
    // the next free slot; rejected values land there and are overwritten.
    // Retry loop (binary search on thresh) guarantees correctness for any
    // data; for N(0,1) rows thresh=2.0 succeeds (~1143 cands, ~4.5/thread,
    // per-thread overflow P~7e-6 -> a handful of block retries per launch).
    float thresh = 2.0f;
    float blo = 0.0f, bhi = 0.0f;
    bool  has_lo = false, has_hi = false;
    float step = 1.0f;
    int   cnt = 0;
    unsigned total = 0;

#define PUT1(x) do { float xv_ = (x); \
                     int idx_ = (cnt < SLOTS) ? cnt : (SLOTS - 1); \
                     buck[bbase + idx_] = xv_; \
                     cnt += (xv_ > thresh) ? 1 : 0; } while (0)
#define PUT4(v) do { PUT1((v).x); PUT1((v).y); PUT1((v).z); PUT1((v).w); } while (0)

    for (int attempt = 0; attempt < 40; ++attempt) {
        if (tid == 0) s_ovf = 0;
        cnt = 0;
        __syncthreads();

        for (int i = tid; i < head; i += BLOCK) PUT1(rp[i]);
        // 4 independent float4 loads in flight before any bucket work.
        for (int it = 0; it < nfull; ++it) {
            const int base = it * (BLOCK * 4) + tid;
            vfloat4 v0 = __builtin_nontemporal_load(&vp[base]);
            vfloat4 v1 = __builtin_nontemporal_load(&vp[base + BLOCK]);
            vfloat4 v2 = __builtin_nontemporal_load(&vp[base + 2 * BLOCK]);
            vfloat4 v3 = __builtin_nontemporal_load(&vp[base + 3 * BLOCK]);
            PUT4(v0); PUT4(v1); PUT4(v2); PUT4(v3);
        }
        for (int i = restart + tid; i < nvec; i += BLOCK) {
            vfloat4 v = __builtin_nontemporal_load(&vp[i]);
            PUT4(v);
        }
        for (int i = tailstart + tid; i < VOCAB; i += BLOCK) PUT1(rp[i]);

        if (cnt > SLOTS) { s_ovf = 1; cnt = SLOTS; }
        s_pfx[tid] = (unsigned)cnt;
        __syncthreads();

        // Inclusive prefix scan over 256 counts (Hillis-Steele).
        for (int off = 1; off < BLOCK; off <<= 1) {
            unsigned add = (tid >= off) ? s_pfx[tid - off] : 0u;
            __syncthreads();
            s_pfx[tid] += add;
            __syncthreads();
        }
        total = s_pfx[BLOCK - 1];
        int ovf = s_ovf;
        if (!ovf && total >= TOPK) break;
        if (ovf) { blo = thresh; has_lo = true; }   // too many per-thread -> raise
        else     { bhi = thresh; has_hi = true; }   // too few overall -> lower
        if (has_lo && has_hi)      thresh = 0.5f * (blo + bhi);
        else if (has_lo)          { thresh = blo + step; step *= 2.0f; }
        else                      { thresh = bhi - step; step *= 2.0f; }
        __syncthreads();
    }

    const int m  = (int)total;          // <= CAND_MAX structurally
    const int kk = (TOPK < m) ? TOPK : m;
    if (m == 0) return;                 // pathological; contributes nothing

    // --- Compaction: stage own bucket in registers, barrier, write packed.
    {
        const unsigned pfx_excl = s_pfx[tid] - (unsigned)cnt;
        float r[SLOTS];
        #pragma unroll
        for (int j = 0; j < SLOTS; ++j) r[j] = buck[bbase + j];
        __syncthreads();
        #pragma unroll
        for (int j = 0; j < SLOTS; ++j)
            if (j < cnt) buck[pfx_excl + j] = r[j];
        __syncthreads();
    }

    // --- Exact radix select (MSB-first, 8-bit digits) for the kk-th largest
    // key among the m compacted candidates. Wave-aggregated histogram
    // atomics: when a whole wave maps to one bin, one leader atomicAdd
    // replaces 64 serialized same-bank atomics.
    unsigned pref = 0, maskhi = 0;
    int remain = kk;
    const int m_pad = ((m + BLOCK - 1) / BLOCK) * BLOCK;

    for (int sh = 24; sh >= 0; sh -= 8) {
        s_hist[tid] = 0;
        __syncthreads();

        for (int i = tid; i < m_pad; i += BLOCK) {
            bool valid = (i < m);
            unsigned key = valid ? fkey(buck[i]) : 0u;
            bool match = valid && ((key & maskhi) == pref);
            unsigned dig = (key >> sh) & 255u;
            unsigned long long mm = __ballot(match);
            if (mm) {
                int leader = __ffsll((unsigned long long)mm) - 1;
                unsigned ldig = __shfl(dig, leader);
                unsigned long long same = __ballot(match && (dig == ldig));
                if (same == mm) {
                    if ((tid & 63) == leader)
                        atomicAdd(&s_hist[ldig], (unsigned)__popcll(mm));
                } else if (match) {
                    atomicAdd(&s_hist[dig], 1u);
                }
            }
        }
        __syncthreads();

        // Suffix sums over 256 bins (Hillis-Steele, s_pfx as scratch).
        s_pfx[tid] = s_hist[tid];
        __syncthreads();
        for (int off = 1; off < 256; off <<= 1) {
            unsigned add = (tid + off < 256) ? s_pfx[tid + off] : 0u;
            __syncthreads();
            s_pfx[tid] += add;
            __syncthreads();
        }
        unsigned my  = s_pfx[tid];
        unsigned nxt = (tid < 255) ? s_pfx[tid + 1] : 0u;
        if ((int)my >= remain && (tid == 255 || (int)nxt < remain)) {
            s_dig = tid;
            s_above = (int)nxt;
        }
        __syncthreads();
        remain -= s_above;
        pref   |= ((unsigned)s_dig) << sh;
        maskhi |= (0xFFu << sh);
        __syncthreads();
    }

    // pref is the exact key of the kk-th largest value t.
    const float tval = unfkey(pref);

    // Sum exp over strictly-greater values; add (kk - c_gt) copies of exp(t)
    // to handle ties exactly like top_k does.
    float psum = 0.0f, pcnt = 0.0f;
    for (int i = tid; i < m; i += BLOCK) {
        float v = buck[i];
        if (fkey(v) > pref) { psum += expf(v); pcnt += 1.0f; }
    }
    for (int off = 32; off > 0; off >>= 1) {
        psum += __shfl_down(psum, off);
        pcnt += __shfl_down(pcnt, off);
    }
    const int lane = tid & 63, wid = tid >> 6;
    if (lane == 0) { s_red0[wid] = psum; s_red1[wid] = pcnt; }
    __syncthreads();
    if (tid == 0) {
        float sum = 0.0f, c = 0.0f;
        for (int w = 0; w < BLOCK / 64; ++w) { sum += s_red0[w]; c += s_red1[w]; }
        sum += ((float)kk - c) * expf(tval);
        float fl = rp[labels[row]];
        float loss = logf(sum) - fl;
        atomicAdd(out, loss * (1.0f / (float)BATCH));
    }
}

extern "C" void kernel_launch(void* const* d_in, const int* in_sizes, int n_in,
                              void* d_out, int out_size, void* d_ws, size_t ws_size,
                              hipStream_t stream) {
    const float* feats  = (const float*)d_in[0];
    const int*   labels = (const int*)d_in[1];
    // d_in[2] holds k = 512; fixed at compile time as TOPK.
    float* out = (float*)d_out;
    (void)in_sizes; (void)n_in; (void)out_size; (void)d_ws; (void)ws_size;

    // d_out is re-poisoned (0xAA) before every replay; zero it on-stream.
    (void)hipMemsetAsync(out, 0, sizeof(float), stream);
    topk_ce_kernel<<<BATCH, BLOCK, 0, stream>>>(feats, labels, out);
}